// Round 3
// baseline (726.966 us; speedup 1.0000x reference)
//
#include <hip/hip_runtime.h>
#include <math.h>

typedef _Float16 f16;
typedef _Float16 f16x8 __attribute__((ext_vector_type(8)));
typedef float    f32x4 __attribute__((ext_vector_type(4)));
typedef unsigned int u32;
typedef unsigned long long u64;

#define NHEADS 128
#define KLEN   8192
#define DDIM   128
#define SDIM   256
#define SCALE  1.2533141373155003f   // sqrt(pi/2)
#define TAU    5e-4f                 // fixup threshold on |proj| (emul err ~1e-6)

// ---- workspace layout ----
// [0, 1MiB)            : qs16  f16 [128 heads][16 q][256 s]
// [1MiB, 1MiB+64KiB)   : Gh_t  f16 [256 s][128 d]   (hi part, transposed)
// [.. +64KiB)          : Gl_t  f16 [256 s][128 d]   (lo part * 4096)
// [2MiB, 2MiB+32MiB)   : packed sign bits, u32[128*8192][8]  (32 B per k-row)
#define QS_OFF     0
#define GH_OFF     (1u << 20)
#define GL_OFF     ((1u << 20) + (64u << 10))
#define PACKED_OFF (2u << 20)

// ------------------------------------------------------------------
// Sequential f32 dot, d-ascending, single-rounding FMA per step.
// Mirrors both BLAS sgemm K-loops and numpy's npyv_muladd AXPY einsum
// path, so near-zero signs match the numpy reference bitwise.
__device__ __forceinline__ float seq_dot_np(const float* __restrict__ a,
                                            const float* __restrict__ bcol) {
  float acc = 0.0f;
  for (int d = 0; d < DDIM; ++d)
    acc = __builtin_fmaf(a[d], bcol[(size_t)d * SDIM], acc);
  return acc;
}

// ------------------------------------------------------------------
// prep: q_sketch = q @ G  (f32 accumulate, store f16)
__global__ void prep_qs_kernel(const float* __restrict__ q,
                               const float* __restrict__ G,
                               f16* __restrict__ qs16) {
  int idx = blockIdx.x * 256 + threadIdx.x;      // 128*16*256 = 524288
  int s  = idx & 255;
  int hq = idx >> 8;                             // head*16 + qrow
  const float* qr = q + (size_t)hq * DDIM;
  float acc = 0.f;
  #pragma unroll 8
  for (int d = 0; d < DDIM; ++d) acc += qr[d] * G[d * SDIM + s];
  qs16[idx] = (f16)acc;
}

// prep: split G into f16 hi + f16 (lo*4096), transposed to [s][d]
__global__ void prep_g_kernel(const float* __restrict__ G,
                              f16* __restrict__ gh, f16* __restrict__ gl) {
  int idx = blockIdx.x * 256 + threadIdx.x;      // 256*128 = 32768
  int d = idx & 127;
  int s = idx >> 7;
  float g = G[d * SDIM + s];
  f16 h = (f16)g;
  gh[s * DDIM + d] = h;
  gl[s * DDIM + d] = (f16)((g - (float)h) * 4096.0f);
}

// ------------------------------------------------------------------
// main: proj = k @ G via f16x3 MFMA emulation; sign; np-mimicking f32
// sequential-FMA recompute for |proj| < TAU; pack sign bits to ws.
// grid: 128 heads * 64 chunks of 128 rows; block 256 (4 waves, 32 rows/wave)
__launch_bounds__(256)
__global__ void proj_sign_kernel(const float* __restrict__ kmat,
                                 const float* __restrict__ G,
                                 const f16* __restrict__ gh,
                                 const f16* __restrict__ gl,
                                 u32* __restrict__ packed) {
  __shared__ __align__(16) char smem[32768];     // 16KB Gh phase + 16KB Gl phase

  const int tid  = threadIdx.x;
  const int lane = tid & 63;
  const int w    = tid >> 6;
  const int wg   = blockIdx.x;
  const int head   = wg >> 6;
  const int kchunk = (wg & 63) * 128;
  const int wavebase = kchunk + w * 32;
  const int g4 = lane >> 4;                      // 0..3
  const int ln = lane & 15;

  // ---- load A fragments for this wave's 32 rows (2 blocks of 16) ----
  // A[m][kk]: m = lane&15, kk = 8*(lane>>4)+j   (16x16x32 f16 layout)
  f16x8 Ah[2][4], Al[2][4];
  #pragma unroll
  for (int rb = 0; rb < 2; ++rb) {
    int row = wavebase + rb * 16 + ln;
    const float* kr = kmat + (size_t)(head * KLEN + row) * DDIM;
    #pragma unroll
    for (int c = 0; c < 4; ++c) {
      const float* p0 = kr + c * 32 + g4 * 8;
      float4 a0 = *(const float4*)p0;
      float4 a1 = *(const float4*)(p0 + 4);
      float af[8] = {a0.x, a0.y, a0.z, a0.w, a1.x, a1.y, a1.z, a1.w};
      f16x8 hh, ll;
      #pragma unroll
      for (int j = 0; j < 8; ++j) {
        f16 h = (f16)af[j];
        hh[j] = h;
        ll[j] = (f16)((af[j] - (float)h) * 4096.0f);
      }
      Ah[rb][c] = hh;
      Al[rb][c] = ll;
    }
  }

  // ---- 4 phases of 64 s each (keeps LDS at 32 KB) ----
  for (int ph = 0; ph < 4; ++ph) {
    __syncthreads();
    {   // stage Gh/Gl phase into LDS, XOR-swizzled: byte ^= (row&7)<<4
      int sl = tid >> 2;                 // 0..63 local s row
      int dp = (tid & 3) * 32;           // d quarter
      int sg = ph * 64 + sl;
      const f16* sh = gh + (size_t)sg * DDIM + dp;
      const f16* slo = gl + (size_t)sg * DDIM + dp;
      #pragma unroll
      for (int i = 0; i < 4; ++i) {
        f16x8 vh = *(const f16x8*)(sh  + i * 8);
        f16x8 vl = *(const f16x8*)(slo + i * 8);
        int off = (sl * 256 + (dp + i * 8) * 2) ^ ((sl & 7) << 4);
        *(f16x8*)(smem + off)         = vh;
        *(f16x8*)(smem + 16384 + off) = vl;
      }
    }
    __syncthreads();

    u32 pw[2][2] = {{0u, 0u}, {0u, 0u}};   // packed u16 tiles for this phase

    #pragma unroll
    for (int tl = 0; tl < 4; ++tl) {        // 4 s-tiles of 16 per phase
      const int sl = tl * 16 + ln;
      // B frags: B[kk][n]: n = lane&15 (s), kk = 8*(lane>>4)+j (d)
      f16x8 Bh[4], Bl[4];
      #pragma unroll
      for (int c = 0; c < 4; ++c) {
        int off = (sl * 256 + c * 64 + g4 * 16) ^ ((sl & 7) << 4);
        Bh[c] = *(const f16x8*)(smem + off);
        Bl[c] = *(const f16x8*)(smem + 16384 + off);
      }
      f32x4 ah0 = {0,0,0,0}, al0 = {0,0,0,0};
      f32x4 ah1 = {0,0,0,0}, al1 = {0,0,0,0};
      #pragma unroll
      for (int c = 0; c < 4; ++c) {
        ah0 = __builtin_amdgcn_mfma_f32_16x16x32_f16(Ah[0][c], Bh[c], ah0, 0, 0, 0);
        al0 = __builtin_amdgcn_mfma_f32_16x16x32_f16(Ah[0][c], Bl[c], al0, 0, 0, 0);
        al0 = __builtin_amdgcn_mfma_f32_16x16x32_f16(Al[0][c], Bh[c], al0, 0, 0, 0);
        ah1 = __builtin_amdgcn_mfma_f32_16x16x32_f16(Ah[1][c], Bh[c], ah1, 0, 0, 0);
        al1 = __builtin_amdgcn_mfma_f32_16x16x32_f16(Ah[1][c], Bl[c], al1, 0, 0, 0);
        al1 = __builtin_amdgcn_mfma_f32_16x16x32_f16(Al[1][c], Bh[c], al1, 0, 0, 0);
      }
      float p[2][4];
      #pragma unroll
      for (int r = 0; r < 4; ++r) {
        p[0][r] = ah0[r] + al0[r] * 2.44140625e-4f;   // 1/4096
        p[1][r] = ah1[r] + al1[r] * 2.44140625e-4f;
      }

      // ---- np-mimicking fixup where |proj| < TAU ----
      // Lane's p[rb][r] is proj[row = wavebase+rb*16+g4*4+r][s = ph*64+sl].
      // Recompute with the exact numpy FMA chain; take its sign.
      #pragma unroll
      for (int rb = 0; rb < 2; ++rb) {
        #pragma unroll
        for (int r = 0; r < 4; ++r) {
          if (__builtin_fabsf(p[rb][r]) < TAU) {
            int row = wavebase + rb * 16 + g4 * 4 + r;
            int sg  = ph * 64 + tl * 16 + ln;
            const float* kr = kmat + (size_t)(head * KLEN + row) * DDIM;
            float acc = seq_dot_np(kr, G + sg);
            p[rb][r] = (acc > 0.0f) ? 1.0f : -1.0f;
          }
        }
      }

      // ---- pack sign bits via ballot ----
      // D layout: value (row=(lane>>4)*4+r, col=lane&15) -> ballot bit `lane`
      #pragma unroll
      for (int rb = 0; rb < 2; ++rb) {
        u64 b0 = __ballot(p[rb][0] > 0.0f ? 1 : 0);
        u64 b1 = __ballot(p[rb][1] > 0.0f ? 1 : 0);
        u64 b2 = __ballot(p[rb][2] > 0.0f ? 1 : 0);
        u64 b3 = __ballot(p[rb][3] > 0.0f ? 1 : 0);
        if (lane < 16) {
          int r = lane & 3;
          u64 b = (r == 0) ? b0 : (r == 1) ? b1 : (r == 2) ? b2 : b3;
          u32 u = (u32)((b >> (16 * (lane >> 2))) & 0xffffu);
          pw[rb][tl >> 1] |= u << (16 * (tl & 1));
        }
      }
    }

    if (lane < 16) {
      #pragma unroll
      for (int rb = 0; rb < 2; ++rb) {
        int row = wavebase + rb * 16 + lane;
        uint2 v; v.x = pw[rb][0]; v.y = pw[rb][1];
        *(uint2*)(packed + (size_t)(head * KLEN + row) * 8 + ph * 2) = v;
      }
    }
  }
}

// ------------------------------------------------------------------
// est = q_sketch @ sign^T, bits -> ±1 f16 on the fly, MFMA f16, f32 out
// grid: 128 heads * 32 chunks of 256 k; block 256 (4 waves, 64 k/wave)
__launch_bounds__(256)
__global__ void est_kernel(const f16* __restrict__ qs16,
                           const u32* __restrict__ packed,
                           float* __restrict__ out) {
  const int tid  = threadIdx.x;
  const int lane = tid & 63;
  const int w    = tid >> 6;
  const int wg   = blockIdx.x;
  const int head   = wg >> 5;
  const int kchunk = (wg & 31) * 256;
  const int g4 = lane >> 4, ln = lane & 15;

  // A frags: qs[q=lane&15][s = 32c + 8*(lane>>4)+j]
  f16x8 aq[8];
  const f16* qb = qs16 + (size_t)head * 16 * SDIM;
  #pragma unroll
  for (int c = 0; c < 8; ++c)
    aq[c] = *(const f16x8*)(qb + ln * SDIM + c * 32 + g4 * 8);

  const int kb = kchunk + w * 64;
  #pragma unroll
  for (int kt = 0; kt < 4; ++kt) {
    int krow = kb + kt * 16 + ln;
    const u32* bp = packed + (size_t)(head * KLEN + krow) * 8;
    uint4 q0 = *(const uint4*)bp;
    uint4 q1 = *(const uint4*)(bp + 4);
    u32 b32[8] = {q0.x, q0.y, q0.z, q0.w, q1.x, q1.y, q1.z, q1.w};
    f32x4 acc = {0, 0, 0, 0};
    #pragma unroll
    for (int c = 0; c < 8; ++c) {
      u32 byte8 = (b32[c] >> (8 * g4)) & 0xffu;
      union { u32 u[4]; f16x8 h; } sv;
      #pragma unroll
      for (int pp = 0; pp < 4; ++pp) {
        u32 v = 0x3C003C00u;                       // +1.0h | +1.0h
        v |= ((byte8 >> (2 * pp))     & 1u) ? 0u : 0x8000u;       // -> -1
        v |= ((byte8 >> (2 * pp + 1)) & 1u) ? 0u : 0x80000000u;
        sv.u[pp] = v;
      }
      acc = __builtin_amdgcn_mfma_f32_16x16x32_f16(aq[c], sv.h, acc, 0, 0, 0);
    }
    float* ob = out + (size_t)(head * 16) * KLEN + kb + kt * 16 + ln;
    #pragma unroll
    for (int r = 0; r < 4; ++r) {
      int qrow = g4 * 4 + r;
      ob[(size_t)qrow * KLEN] = acc[r] * SCALE;
    }
  }
}

// ------------------------------------------------------------------
extern "C" void kernel_launch(void* const* d_in, const int* in_sizes, int n_in,
                              void* d_out, int out_size, void* d_ws, size_t ws_size,
                              hipStream_t stream) {
  const float* q = (const float*)d_in[0];
  const float* k = (const float*)d_in[1];
  const float* G = (const float*)d_in[2];
  float* out = (float*)d_out;
  char* ws = (char*)d_ws;

  f16* qs16  = (f16*)(ws + QS_OFF);
  f16* gh    = (f16*)(ws + GH_OFF);
  f16* gl    = (f16*)(ws + GL_OFF);
  u32* packed = (u32*)(ws + PACKED_OFF);

  prep_qs_kernel<<<2048, 256, 0, stream>>>(q, G, qs16);
  prep_g_kernel<<<128, 256, 0, stream>>>(G, gh, gl);
  proj_sign_kernel<<<8192, 256, 0, stream>>>(k, G, gh, gl, packed);
  est_kernel<<<4096, 256, 0, stream>>>(qs16, packed, out);
}